// Round 12
// baseline (344.930 us; speedup 1.0000x reference)
//
#include <hip/hip_runtime.h>

// SNNLinear, exact-trajectory i8-digit MFMA. Round 12: GEMM+SCAN fully fused.
//   Block = (n16 o-group, b16 batch-group), 256 blocks, 256 threads.
//   Waves K-split: wave w owns kt in [4w,4w+4); its 20 B digit-fragments
//   (4 kt x 5 planes) are register-resident for the whole kernel (B read
//   ONCE per block). Per t: 20 MFMA -> exact i64 Horner partials -> LDS
//   (double-buffered, one barrier/t) -> per-thread 4-partial sum -> f64 du
//   (bit-identical to R8's value) -> membrane update in registers.
//   du is NEVER materialized to global; no Lo, no scan dispatch.
//   Software-pipelined: MFMA(t) issues before process(t-1) so the matrix
//   pipe stays busy across the barrier.
// Math proven R3-R11: Wq=round(W*2^36), 5 balanced base-256 i8 digit planes;
// mfma_i32_16x16x64_i8 exact (i32 sums < 2^18); K-split partial Horner sums
// add exactly in i64; du = (double)tot*2^-36 + bias (same value as R8).
// Outputs: ss[100,64,1024] | mem_out[64,1024] | hat_s[64,1024]
// ws: [0,6.55M) A8 ; [6.55M,11.8M) Bt

typedef __attribute__((ext_vector_type(4))) int int4v;

#define T_STEPS 100
#define BO 65536
#define K_DIM 1024
#define A8_OFF 0
#define BT_OFF 6553600

// ---- merged prepass (R11 verbatim): spikes -> A8 frags ; W -> Bt planes ----
__global__ __launch_bounds__(256)
void prepass(const float* __restrict__ S, const float* __restrict__ W,
             signed char* __restrict__ A8, signed char* __restrict__ Bt) {
    const int bid = blockIdx.x;
    if (bid < 1600) {
        const int id = bid * 256 + threadIdx.x;          // 0..409599
        const int m = id >> 6, ks = id & 63;
        const float* sp = S + (size_t)m * K_DIM + ks * 16;
        const float4 s0 = *(const float4*)(sp);
        const float4 s1 = *(const float4*)(sp + 4);
        const float4 s2 = *(const float4*)(sp + 8);
        const float4 s3 = *(const float4*)(sp + 12);
        const float sv[16] = {s0.x,s0.y,s0.z,s0.w, s1.x,s1.y,s1.z,s1.w,
                              s2.x,s2.y,s2.z,s2.w, s3.x,s3.y,s3.z,s3.w};
        union { signed char c[16]; int4v v; } u;
#pragma unroll
        for (int e = 0; e < 16; ++e) u.c[e] = (signed char)sv[e];   // exact 0/1
        const size_t off = ((size_t)(m >> 4) * 16 + (ks >> 2)) * 1024
                         + (size_t)((ks & 3) * 16 + (m & 15)) * 16;
        *(int4v*)(A8 + off) = u.v;
    } else {
        const int id = (bid - 1600) * 256 + threadIdx.x; // 0..65535
        const int n = id >> 6, ks = id & 63;
        const float* wp = W + (size_t)n * K_DIM + ks * 16;
        const float4 w0 = *(const float4*)(wp);
        const float4 w1 = *(const float4*)(wp + 4);
        const float4 w2 = *(const float4*)(wp + 8);
        const float4 w3 = *(const float4*)(wp + 12);
        const float wv[16] = {w0.x,w0.y,w0.z,w0.w, w1.x,w1.y,w1.z,w1.w,
                              w2.x,w2.y,w2.z,w2.w, w3.x,w3.y,w3.z,w3.w};
        union { signed char c[16]; int4v v; } u[5];
#pragma unroll
        for (int e = 0; e < 16; ++e) {
            long long q = llrint((double)wv[e] * 0x1p36);   // |q| < 2^39
#pragma unroll
            for (int p = 0; p < 4; ++p) {
                const int d = (int)(((q + 128) & 255) - 128);  // [-128,127]
                u[p].c[e] = (signed char)d;
                q = (q - d) >> 8;                              // exact
            }
            u[4].c[e] = (signed char)q;                        // |d4| <= ~90
        }
        const size_t base = ((size_t)(n >> 4) * 16 + (ks >> 2)) * 5 * 1024
                          + (size_t)((ks & 3) * 16 + (n & 15)) * 16;
#pragma unroll
        for (int p = 0; p < 5; ++p)
            *(int4v*)(Bt + base + (size_t)p * 1024) = u[p].v;
    }
}

// ---- fused GEMM + scan ----
__global__ __launch_bounds__(256, 1)
void fused(const signed char* __restrict__ A8,
           const signed char* __restrict__ Bt,
           const float* __restrict__ bias,
           const float* __restrict__ mem0,
           float* __restrict__ out) {
    // partials: [slot][( b_loc*16 + o_loc )*5 + w]  (5th entry = pad)
    __shared__ long long part[2][1280];
    const int bid = blockIdx.x;      // 0..255
    const int n16 = bid >> 2;        // 0..63
    const int b16 = bid & 3;         // 0..3
    const int tid = threadIdx.x;
    const int lane = tid & 63, w = tid >> 6;
    const int quad = lane >> 4, r16 = lane & 15;

    // B digit fragments, register-resident: kt in [4w, 4w+4), 5 planes
    int4v bf[4][5];
    {
        const signed char* Bb = Bt + (size_t)n16 * 81920 + (size_t)lane * 16;
#pragma unroll
        for (int j = 0; j < 4; ++j)
#pragma unroll
            for (int p = 0; p < 5; ++p)
                bf[j][p] = *(const int4v*)(Bb + (size_t)((4 * w + j) * 5 + p) * 1024);
    }

    // A base for (b16, wave-k-slice); group g(t) = t*4 + b16, stride 64 KB/t
    const signed char* Ab = A8 + (size_t)b16 * 16384
                               + (size_t)(4 * w) * 1024 + (size_t)lane * 16;

    // scan state (one chain per thread)
    const int b_l = tid >> 4, o_l = tid & 15;
    const int o_g = n16 * 16 + o_l;
    const size_t col = (size_t)(b16 * 16 + b_l) * 1024 + o_g;
    double m = (double)mem0[col];
    double cnt = 0.0;
    const double bd = (double)bias[o_g];

    int4v a[2][4];
    int4v acc[2][5];

    auto loadA = [&](int t) {
        const int s = t & 1;
        const signed char* at = Ab + (size_t)t * 65536;
#pragma unroll
        for (int j = 0; j < 4; ++j)
            a[s][j] = *(const int4v*)(at + (size_t)j * 1024);
    };
    auto mfma_t = [&](int t) {
        const int s = t & 1;
        const int4v zero = {0, 0, 0, 0};
#pragma unroll
        for (int p = 0; p < 5; ++p)
            acc[s][p] = __builtin_amdgcn_mfma_i32_16x16x64_i8(
                a[s][0], bf[0][p], zero, 0, 0, 0);
#pragma unroll
        for (int j = 1; j < 4; ++j)
#pragma unroll
            for (int p = 0; p < 5; ++p)
                acc[s][p] = __builtin_amdgcn_mfma_i32_16x16x64_i8(
                    a[s][j], bf[j][p], acc[s][p], 0, 0, 0);
    };
    auto process = [&](int t) {
        const int s = t & 1;
        // exact i64 Horner of this wave's 5 plane-partials, per element
#pragma unroll
        for (int e = 0; e < 4; ++e) {
            long long v = (long long)acc[s][4][e];
            v = v * 256 + (long long)acc[s][3][e];
            v = v * 256 + (long long)acc[s][2][e];
            v = v * 256 + (long long)acc[s][1][e];
            v = v * 256 + (long long)acc[s][0][e];
            part[s][((quad * 4 + e) * 16 + r16) * 5 + w] = v;
        }
        __syncthreads();
        const long long* pc = &part[s][(b_l * 16 + o_l) * 5];
        const long long tot = pc[0] + pc[1] + pc[2] + pc[3];   // exact
        const double du = (double)tot * 0x1p-36 + bd;          // == R8's du
        m += du;
        const double sp = (m > 15.0) ? 1.0 : 0.0;
        m = fmin(fmax(m, 0.0), 15.0);
        out[(size_t)t * BO + col] = (float)sp;
        cnt += sp;
        m -= m * sp;
    };

    loadA(0);
    for (int t = 0; t < T_STEPS; ++t) {
        if (t + 1 < T_STEPS) loadA(t + 1);
        mfma_t(t);                 // matrix pipe busy across process(t-1)'s barrier
        if (t > 0) process(t - 1);
    }
    process(T_STEPS - 1);

    out[(size_t)T_STEPS * BO + col] = (float)m;                  // mem_out
    out[(size_t)(T_STEPS + 1) * BO + col] = (float)(cnt * 0.01); // hat_s
}

extern "C" void kernel_launch(void* const* d_in, const int* in_sizes, int n_in,
                              void* d_out, int out_size, void* d_ws, size_t ws_size,
                              hipStream_t stream) {
    const float* spikes = (const float*)d_in[0];  // [100,64,1024]
    const float* mem    = (const float*)d_in[1];  // [64,1024]
    // d_in[2] = hat_spikes: dead in forward
    const float* W      = (const float*)d_in[3];  // [1024,1024]
    const float* b      = (const float*)d_in[4];  // [1024]
    float* out = (float*)d_out;
    signed char* A8 = (signed char*)d_ws + A8_OFF;
    signed char* Bt = (signed char*)d_ws + BT_OFF;

    prepass<<<dim3(1856), 256, 0, stream>>>(spikes, W, A8, Bt);
    fused<<<dim3(256), 256, 0, stream>>>(A8, Bt, b, mem, out);
}

// Round 13
// 151.881 us; speedup vs baseline: 2.2711x; 2.2711x over previous
//
#include <hip/hip_runtime.h>

// SNNLinear, exact-trajectory i8-digit MFMA. Round 13 = R11 (proven 153us)
// with two local fixes:
//   1) prepass remapped wave-per-fragment-tile: lane L computes the 16
//      elements of fragment slot L and stores at base+L*16 -> perfectly
//      coalesced 1KB/wave writes (old layout scattered 16B at 256B stride,
//      ~4x write amplification; prepass measured ~60-75us via R12's gap).
//   2) scan prefetch deepened to 3 groups (12 t) ahead, 4-slot ring.
// GEMM kernel is R11 verbatim (58.5us, MfmaUtil 22%).
// Math proven R3-R12 (bit-identical): Wq=round(W*2^36), 5 balanced base-256
// i8 digit planes; mfma_i32_16x16x64_i8 exact; i64 Horner -> f64 du ->
// f32 hi (ss region) + f16 lo*2^12 (ws). Scan in f64.
// Outputs: ss[100,64,1024] | mem_out[64,1024] | hat_s[64,1024]
// ws: [0,6.55M) A8 ; [6.55M,11.8M) Bt ; [11.8M,24.9M) Lo

typedef __attribute__((ext_vector_type(4))) int int4v;

#define T_STEPS 100
#define BO 65536
#define K_DIM 1024
#define A8_OFF 0
#define BT_OFF 6553600
#define LO_OFF 11796480

// ---- prepass, fragment-coalesced: wave = one (m16|n16, k64) tile ----
__global__ __launch_bounds__(256)
void prepass(const float* __restrict__ S, const float* __restrict__ W,
             signed char* __restrict__ A8, signed char* __restrict__ Bt) {
    const int wave = blockIdx.x * 4 + (threadIdx.x >> 6);  // 0..7423
    const int lane = threadIdx.x & 63;
    const int r16 = lane & 15, quad = lane >> 4;

    if (wave < 6400) {
        // spikes -> A8: tile (m16, k64); lane writes frag slot lane.
        const int m16 = wave >> 4, k64 = wave & 15;
        const int m = m16 * 16 + r16;
        const float* sp = S + (size_t)m * K_DIM + k64 * 64 + quad * 16;
        const float4 s0 = *(const float4*)(sp);
        const float4 s1 = *(const float4*)(sp + 4);
        const float4 s2 = *(const float4*)(sp + 8);
        const float4 s3 = *(const float4*)(sp + 12);
        const float sv[16] = {s0.x,s0.y,s0.z,s0.w, s1.x,s1.y,s1.z,s1.w,
                              s2.x,s2.y,s2.z,s2.w, s3.x,s3.y,s3.z,s3.w};
        union { signed char c[16]; int4v v; } u;
#pragma unroll
        for (int e = 0; e < 16; ++e) u.c[e] = (signed char)sv[e];   // exact 0/1
        *(int4v*)(A8 + ((size_t)(m16 * 16 + k64) * 1024) + lane * 16) = u.v;
    } else {
        // W -> Bt: tile (n16, k64); lane writes frag slot lane, 5 planes.
        const int t2 = wave - 6400;                 // 0..1023
        const int n16 = t2 >> 4, k64 = t2 & 15;
        const int n = n16 * 16 + r16;
        const float* wp = W + (size_t)n * K_DIM + k64 * 64 + quad * 16;
        const float4 w0 = *(const float4*)(wp);
        const float4 w1 = *(const float4*)(wp + 4);
        const float4 w2 = *(const float4*)(wp + 8);
        const float4 w3 = *(const float4*)(wp + 12);
        const float wv[16] = {w0.x,w0.y,w0.z,w0.w, w1.x,w1.y,w1.z,w1.w,
                              w2.x,w2.y,w2.z,w2.w, w3.x,w3.y,w3.z,w3.w};
        union { signed char c[16]; int4v v; } u[5];
#pragma unroll
        for (int e = 0; e < 16; ++e) {
            long long q = llrint((double)wv[e] * 0x1p36);   // |q| < 2^39
#pragma unroll
            for (int p = 0; p < 4; ++p) {
                const int d = (int)(((q + 128) & 255) - 128);  // [-128,127]
                u[p].c[e] = (signed char)d;
                q = (q - d) >> 8;                              // exact
            }
            u[4].c[e] = (signed char)q;                        // |d4| <= ~115
        }
        signed char* base = Bt + (size_t)(n16 * 16 + k64) * 5 * 1024 + lane * 16;
#pragma unroll
        for (int p = 0; p < 5; ++p)
            *(int4v*)(base + (size_t)p * 1024) = u[p].v;
    }
}

// ---- GEMM (R11 verbatim): block 128m x 32n, 4 waves, no LDS/barriers ----
__global__ __launch_bounds__(256)
void gemm_i8(const signed char* __restrict__ A8,
             const signed char* __restrict__ Bt,
             const float* __restrict__ bias,
             float* __restrict__ Chi,          // hi -> ss region
             _Float16* __restrict__ Lo) {      // lo*4096 residual
    const int bid = blockIdx.x;                // 0..1599
    const int xcd = bid & 7;
    const int t_  = bid >> 3;
    const int cu  = t_ & 31;
    const int rnd = t_ >> 5;
    const int bn = (xcd << 2) | (cu & 3);      // 0..31
    const int bm = (cu >> 2) + (rnd << 3);     // 0..49

    const int tid = threadIdx.x;
    const int lane = tid & 63, wid = tid >> 6;
    const int wm = wid >> 1, wn = wid & 1;
    const int quad = lane >> 4, r16 = lane & 15;
    const int mgb = bm * 8 + wm * 4;
    const int ng  = bn * 2 + wn;

    const signed char* Ab = A8 + (size_t)mgb * 16384 + (size_t)lane * 16;
    const signed char* Bb = Bt + (size_t)ng * 81920 + (size_t)lane * 16;

    int4v a0[4], a1[4], b0[5], b1[5];
    int4v acc[4][5] = {};

    auto loadA = [&](int kt, int4v* a) {
#pragma unroll
        for (int i = 0; i < 4; ++i)
            a[i] = *(const int4v*)(Ab + (size_t)(i * 16 + kt) * 1024);
    };
    auto loadB = [&](int kt, int4v* b) {
#pragma unroll
        for (int p = 0; p < 5; ++p)
            b[p] = *(const int4v*)(Bb + (size_t)(kt * 5 + p) * 1024);
    };
    auto mf = [&](const int4v* a, const int4v* b) {
#pragma unroll
        for (int p = 0; p < 5; ++p)
#pragma unroll
            for (int i = 0; i < 4; ++i)
                acc[i][p] = __builtin_amdgcn_mfma_i32_16x16x64_i8(
                    a[i], b[p], acc[i][p], 0, 0, 0);
    };

    loadA(0, a0); loadB(0, b0);
    loadA(1, a1); loadB(1, b1);
    for (int kt = 0; kt < 16; kt += 2) {
        mf(a0, b0);
        if (kt + 2 < 16) { loadA(kt + 2, a0); loadB(kt + 2, b0); }
        mf(a1, b1);
        if (kt + 3 < 16) { loadA(kt + 3, a1); loadB(kt + 3, b1); }
    }

    const int n_g = bn * 32 + wn * 16 + r16;
    const double bd = (double)bias[n_g];
#pragma unroll
    for (int i = 0; i < 4; ++i)
#pragma unroll
        for (int e = 0; e < 4; ++e) {
            long long t = (long long)acc[i][4][e];
            t = t * 256 + (long long)acc[i][3][e];
            t = t * 256 + (long long)acc[i][2][e];
            t = t * 256 + (long long)acc[i][1][e];
            t = t * 256 + (long long)acc[i][0][e];   // exact, |t| < 2^50
            const double du = (double)t * 0x1p-36 + bd;
            const float hi = (float)du;
            const float lo = (float)(du - (double)hi);
            const size_t m_g = (size_t)(bm * 128 + wm * 64 + i * 16 + quad * 4 + e);
            const size_t off = m_g * 1024 + n_g;
            Chi[off] = hi;
            Lo[off] = (_Float16)(lo * 4096.0f);
        }
}

// ---- membrane scan, f64, in place; 4-slot ring, 3 groups (12 t) ahead ----
__global__ __launch_bounds__(256)
void snn_scan(float* __restrict__ out, const _Float16* __restrict__ lo,
              const float* __restrict__ mem0) {
    const int bo = blockIdx.x * 256 + threadIdx.x;
    double m = (double)mem0[bo];
    double cnt = 0.0;
    float h[4][4], l[4][4];
#pragma unroll
    for (int s = 0; s < 3; ++s)
#pragma unroll
        for (int u = 0; u < 4; ++u) {
            const size_t idx = (size_t)(s * 4 + u) * BO + bo;
            h[s][u] = out[idx];
            l[s][u] = (float)lo[idx];
        }
#pragma unroll
    for (int g = 0; g < 25; ++g) {
        const int cs = g & 3, ps = (g + 3) & 3;
        if (g + 3 < 25) {
#pragma unroll
            for (int u = 0; u < 4; ++u) {
                const size_t idx = (size_t)((g + 3) * 4 + u) * BO + bo;
                h[ps][u] = out[idx];
                l[ps][u] = (float)lo[idx];
            }
        }
#pragma unroll
        for (int u = 0; u < 4; ++u) {
            const double du = (double)h[cs][u] + (double)l[cs][u] * 0x1p-12;
            m += du;
            const double s = (m > 15.0) ? 1.0 : 0.0;
            m = fmin(fmax(m, 0.0), 15.0);
            out[(size_t)(g * 4 + u) * BO + bo] = (float)s;
            cnt += s;
            m -= m * s;
        }
    }
    out[(size_t)T_STEPS * BO + bo] = (float)m;
    out[(size_t)(T_STEPS + 1) * BO + bo] = (float)(cnt * 0.01);
}

extern "C" void kernel_launch(void* const* d_in, const int* in_sizes, int n_in,
                              void* d_out, int out_size, void* d_ws, size_t ws_size,
                              hipStream_t stream) {
    const float* spikes = (const float*)d_in[0];  // [100,64,1024]
    const float* mem    = (const float*)d_in[1];  // [64,1024]
    // d_in[2] = hat_spikes: dead in forward
    const float* W      = (const float*)d_in[3];  // [1024,1024]
    const float* b      = (const float*)d_in[4];  // [1024]
    float* out = (float*)d_out;
    signed char* A8 = (signed char*)d_ws + A8_OFF;
    signed char* Bt = (signed char*)d_ws + BT_OFF;
    _Float16*    Lo = (_Float16*)((char*)d_ws + LO_OFF);

    prepass<<<dim3(1856), 256, 0, stream>>>(spikes, W, A8, Bt);
    gemm_i8<<<dim3(1600), 256, 0, stream>>>(A8, Bt, b, out, Lo);
    snn_scan<<<dim3(BO / 256), 256, 0, stream>>>(out, Lo, mem);
}